// Round 1
// baseline (1300.710 us; speedup 1.0000x reference)
//
#include <hip/hip_runtime.h>
#include <math.h>

#define LB __launch_bounds__(256)

constexpr int BATCH = 32, NFEAT = 1024, FDIM = 768, NSLOT = 24, DDIM = 256;
constexpr int NH = 4, DH = 64, CBN = 512, NITER = 3;
constexpr int MF = BATCH * NFEAT;   // 32768 feature rows
constexpr int MS = BATCH * NSLOT;   // 768 slot rows
constexpr float QSCALE = 0.125f;    // dh^-0.5
constexpr float ATTN_EPS = 1e-8f;
constexpr float LNEPS = 1e-5f;

// ---------------- per-row mean/rstd of features (for fused LN) ----------------
__global__ LB void k_rowstats(const float* __restrict__ x, float* __restrict__ stats) {
  const int row = blockIdx.x;
  const int t = threadIdx.x;
  const float* xr = x + (size_t)row * FDIM;
  float s = 0.f, sq = 0.f;
  for (int c = t; c < FDIM; c += 256) { float v = xr[c]; s += v; sq += v * v; }
  __shared__ float ls[256], lq[256];
  ls[t] = s; lq[t] = sq; __syncthreads();
  for (int o = 128; o > 0; o >>= 1) {
    if (t < o) { ls[t] += ls[t + o]; lq[t] += lq[t + o]; }
    __syncthreads();
  }
  if (t == 0) {
    float m = ls[0] / (float)FDIM;
    float var = lq[0] / (float)FDIM - m * m;
    stats[row * 2] = m;
    stats[row * 2 + 1] = 1.f / sqrtf(var + LNEPS);
  }
}

// -------- fused LN(features) @ [Wk;Wv]^T -> k [32768,256], v [32768,256] --------
// tiles: 128x128, BK=16, 256 threads, 8x8 per thread
__global__ LB void k_lnkv(const float* __restrict__ x, const float* __restrict__ stats,
                          const float* __restrict__ gamma, const float* __restrict__ beta,
                          const float* __restrict__ Wk, const float* __restrict__ Wv,
                          float* __restrict__ kout, float* __restrict__ vout) {
  __shared__ float As[16][128];
  __shared__ float Bs[16][128];
  const int row0 = blockIdx.x * 128;
  const int col0 = blockIdx.y * 128;       // 0,128 -> k ; 256,384 -> v
  const float* W = (col0 < 256) ? Wk : Wv;
  const int wc0 = col0 & 255;
  float* Cout = (col0 < 256) ? kout : vout;
  const int t = threadIdx.x;
  const int lm = t >> 1;                    // 0..127 staging row
  const int lk = (t & 1) * 8;               // 0 or 8
  const int tm0 = (t >> 4) * 8;
  const int tn0 = (t & 15) * 8;
  const float mrow = stats[(row0 + lm) * 2];
  const float rrow = stats[(row0 + lm) * 2 + 1];
  const float* arow = x + (size_t)(row0 + lm) * FDIM;
  const float* wrow = W + (size_t)(wc0 + lm) * FDIM;
  float acc[8][8] = {};
  for (int k0 = 0; k0 < FDIM; k0 += 16) {
#pragma unroll
    for (int h = 0; h < 2; ++h) {
      const int kk = lk + h * 4;
      float4 av = *(const float4*)(arow + k0 + kk);
      float4 gv = *(const float4*)(gamma + k0 + kk);
      float4 bv = *(const float4*)(beta + k0 + kk);
      As[kk + 0][lm] = (av.x - mrow) * rrow * gv.x + bv.x;
      As[kk + 1][lm] = (av.y - mrow) * rrow * gv.y + bv.y;
      As[kk + 2][lm] = (av.z - mrow) * rrow * gv.z + bv.z;
      As[kk + 3][lm] = (av.w - mrow) * rrow * gv.w + bv.w;
      float4 wv4 = *(const float4*)(wrow + k0 + kk);
      Bs[kk + 0][lm] = wv4.x;
      Bs[kk + 1][lm] = wv4.y;
      Bs[kk + 2][lm] = wv4.z;
      Bs[kk + 3][lm] = wv4.w;
    }
    __syncthreads();
#pragma unroll
    for (int kk = 0; kk < 16; ++kk) {
      float a[8], b[8];
      *(float4*)&a[0] = *(const float4*)&As[kk][tm0];
      *(float4*)&a[4] = *(const float4*)&As[kk][tm0 + 4];
      *(float4*)&b[0] = *(const float4*)&Bs[kk][tn0];
      *(float4*)&b[4] = *(const float4*)&Bs[kk][tn0 + 4];
#pragma unroll
      for (int i = 0; i < 8; ++i)
#pragma unroll
        for (int j = 0; j < 8; ++j) acc[i][j] += a[i] * b[j];
    }
    __syncthreads();
  }
#pragma unroll
  for (int i = 0; i < 8; ++i) {
    float* cr = Cout + (size_t)(row0 + tm0 + i) * 256 + wc0 + tn0;
    *(float4*)cr = make_float4(acc[i][0], acc[i][1], acc[i][2], acc[i][3]);
    *(float4*)(cr + 4) = make_float4(acc[i][4], acc[i][5], acc[i][6], acc[i][7]);
  }
}

// ---------------- LN over slots rows (256-wide) ----------------
__global__ LB void k_ln_vec(const float* __restrict__ x, const float* __restrict__ g,
                            const float* __restrict__ bb, float* __restrict__ out) {
  const int r = blockIdx.x;
  const int t = threadIdx.x;
  __shared__ float red[256];
  float v = x[(size_t)r * 256 + t];
  red[t] = v; __syncthreads();
  for (int o = 128; o > 0; o >>= 1) { if (t < o) red[t] += red[t + o]; __syncthreads(); }
  float m = red[0] / 256.f;
  __syncthreads();
  float dv = v - m;
  red[t] = dv * dv; __syncthreads();
  for (int o = 128; o > 0; o >>= 1) { if (t < o) red[t] += red[t + o]; __syncthreads(); }
  float rs = 1.f / sqrtf(red[0] / 256.f + LNEPS);
  out[(size_t)r * 256 + t] = dv * rs * g[t] + bb[t];
}

// ------------- generic C[M,Nc] = A[M,256] @ W[Nc,256]^T (+bias) -------------
// tiles 64x64, BK=16, 256 threads, 4x4 per thread
template <bool BIAS>
__global__ LB void k_gemm_nt(const float* __restrict__ A, const float* __restrict__ W,
                             const float* __restrict__ bias, float* __restrict__ C,
                             int Nc) {
  __shared__ float As[16][64];
  __shared__ float Bs[16][64];
  const int row0 = blockIdx.x * 64;
  const int col0 = blockIdx.y * 64;
  const int t = threadIdx.x;
  const int lm = t >> 2;
  const int lk = (t & 3) * 4;
  const int tm0 = (t >> 4) * 4;
  const int tn0 = (t & 15) * 4;
  const float* arow = A + (size_t)(row0 + lm) * 256;
  const float* wrow = W + (size_t)(col0 + lm) * 256;
  float acc[4][4] = {};
  for (int k0 = 0; k0 < 256; k0 += 16) {
    float4 av = *(const float4*)(arow + k0 + lk);
    As[lk + 0][lm] = av.x; As[lk + 1][lm] = av.y; As[lk + 2][lm] = av.z; As[lk + 3][lm] = av.w;
    float4 wv = *(const float4*)(wrow + k0 + lk);
    Bs[lk + 0][lm] = wv.x; Bs[lk + 1][lm] = wv.y; Bs[lk + 2][lm] = wv.z; Bs[lk + 3][lm] = wv.w;
    __syncthreads();
#pragma unroll
    for (int kk = 0; kk < 16; ++kk) {
      float a[4], b[4];
      *(float4*)a = *(const float4*)&As[kk][tm0];
      *(float4*)b = *(const float4*)&Bs[kk][tn0];
#pragma unroll
      for (int i = 0; i < 4; ++i)
#pragma unroll
        for (int j = 0; j < 4; ++j) acc[i][j] += a[i] * b[j];
    }
    __syncthreads();
  }
#pragma unroll
  for (int i = 0; i < 4; ++i) {
    float4 o = make_float4(acc[i][0], acc[i][1], acc[i][2], acc[i][3]);
    if (BIAS) {
      const float4 bv = *(const float4*)(bias + col0 + tn0);
      o.x += bv.x; o.y += bv.y; o.z += bv.z; o.w += bv.w;
    }
    *(float4*)(C + (size_t)(row0 + tm0 + i) * Nc + col0 + tn0) = o;
  }
}

// ---- dots = scale * q k^T, softmax over slots (i), write attn[b][h][i][j] ----
// one block per (b, h, 256-wide j chunk); thread owns one j, 24 slots in regs
__global__ LB void k_dots(const float* __restrict__ q, const float* __restrict__ kmat,
                          float* __restrict__ attn) {
  const int blk = blockIdx.x;
  const int jc = blk & 3;
  const int h = (blk >> 2) & 3;
  const int b = blk >> 4;
  const int t = threadIdx.x;
  __shared__ float qs[NSLOT][DH];
  for (int l = t; l < NSLOT * DH; l += 256) {
    int i = l >> 6, d = l & 63;
    qs[i][d] = q[(size_t)(b * NSLOT + i) * 256 + h * 64 + d];
  }
  __syncthreads();
  const int j = jc * 256 + t;
  const float* kr = kmat + (size_t)(b * NFEAT + j) * 256 + h * 64;
  float acc[NSLOT] = {};
#pragma unroll
  for (int d4 = 0; d4 < DH; d4 += 4) {
    float4 kv = *(const float4*)(kr + d4);
#pragma unroll
    for (int i = 0; i < NSLOT; ++i)
      acc[i] += qs[i][d4] * kv.x + qs[i][d4 + 1] * kv.y + qs[i][d4 + 2] * kv.z + qs[i][d4 + 3] * kv.w;
  }
  float mx = -1e30f;
#pragma unroll
  for (int i = 0; i < NSLOT; ++i) { acc[i] *= QSCALE; mx = fmaxf(mx, acc[i]); }
  float s = 0.f;
#pragma unroll
  for (int i = 0; i < NSLOT; ++i) { acc[i] = expf(acc[i] - mx); s += acc[i]; }
  const float inv = 1.f / s;
  float* ab = attn + (size_t)(b * NH + h) * NSLOT * NFEAT + j;
#pragma unroll
  for (int i = 0; i < NSLOT; ++i) ab[(size_t)i * NFEAT] = acc[i] * inv;
}

// ---- upd[b,i,h,:] = sum_j (attn+eps)[b,i,h,j] v[b,j,h,:] / sum_j(attn+eps) ----
// one block per (b,h); 256 threads: d = t&63, each owns 6 slots
__global__ LB void k_upd(const float* __restrict__ attn, const float* __restrict__ vmat,
                         float* __restrict__ upd) {
  const int h = blockIdx.x & 3;
  const int b = blockIdx.x >> 2;
  const int t = threadIdx.x;
  __shared__ float at[NSLOT][64];
  __shared__ float vt[64][64];
  __shared__ float ssum[NSLOT];
  if (t < NSLOT) ssum[t] = 0.f;
  const int d = t & 63;
  const int ig = t >> 6;  // 0..3 -> slots ig*6..ig*6+5
  float acc[6] = {};
  const float* ab = attn + (size_t)(b * NH + h) * NSLOT * NFEAT;
  for (int j0 = 0; j0 < NFEAT; j0 += 64) {
    __syncthreads();
    for (int l = t; l < NSLOT * 64; l += 256) {
      int i = l >> 6, jj = l & 63;
      at[i][jj] = ab[(size_t)i * NFEAT + j0 + jj] + ATTN_EPS;
    }
#pragma unroll
    for (int r = 0; r < 4; ++r) {
      int l = r * 1024 + t * 4;
      int jj = l >> 6, dd = l & 63;
      *(float4*)&vt[jj][dd] = *(const float4*)(vmat + (size_t)(b * NFEAT + j0 + jj) * 256 + h * 64 + dd);
    }
    __syncthreads();
    if (t < NSLOT) {
      float s = 0.f;
      for (int jj = 0; jj < 64; ++jj) s += at[t][jj];
      ssum[t] += s;
    }
    for (int jj = 0; jj < 64; ++jj) {
      float vv = vt[jj][d];
#pragma unroll
      for (int u = 0; u < 6; ++u) acc[u] += at[ig * 6 + u][jj] * vv;
    }
  }
  __syncthreads();
#pragma unroll
  for (int u = 0; u < 6; ++u) {
    int i = ig * 6 + u;
    upd[(size_t)(b * NSLOT + i) * 256 + h * 64 + d] = acc[u] / ssum[i];
  }
}

// ---------------- GRU elementwise (in-place slots update) ----------------
__global__ LB void k_gru(const float* __restrict__ gi, const float* __restrict__ gh,
                         float* __restrict__ slots) {
  const int r = blockIdx.x;
  const int o = threadIdx.x;
  const size_t base = (size_t)r * 768;
  float ir = gi[base + o], iz = gi[base + o + 256], inn = gi[base + o + 512];
  float hr = gh[base + o], hz = gh[base + o + 256], hn = gh[base + o + 512];
  float rr = 1.f / (1.f + expf(-(ir + hr)));
  float z = 1.f / (1.f + expf(-(iz + hz)));
  float n = tanhf(inn + rr * hn);
  float hp = slots[(size_t)r * 256 + o];
  slots[(size_t)r * 256 + o] = (1.f - z) * n + z * hp;
}

// ---------------- attn_vis = mean over heads -> output ----------------
__global__ LB void k_attnvis(const float* __restrict__ attn, float* __restrict__ out) {
  const int idx = blockIdx.x * 256 + threadIdx.x;  // over B*NSLOT*NFEAT
  const int j = idx & 1023;
  const int rem = idx >> 10;       // b*NSLOT + i
  const int i = rem % NSLOT;
  const int b = rem / NSLOT;
  float s = 0.f;
#pragma unroll
  for (int h = 0; h < NH; ++h)
    s += attn[(size_t)((b * NH + h) * NSLOT + i) * NFEAT + j];
  out[idx] = 0.25f * s;
}

// ---- VQ: argmin over codebook (ref formula x2 - 2xc + c2), straight-through ----
__global__ LB void k_vq(float* __restrict__ slots, const float* __restrict__ cb,
                        float* __restrict__ idx_out, float* __restrict__ bestd2) {
  const int r = blockIdx.x;
  const int t = threadIdx.x;
  __shared__ float xs[256];
  __shared__ float red[256];
  __shared__ float rv[256];
  __shared__ int ri[256];
  xs[t] = slots[(size_t)r * 256 + t];
  __syncthreads();
  red[t] = xs[t] * xs[t]; __syncthreads();
  for (int o = 128; o > 0; o >>= 1) { if (t < o) red[t] += red[t + o]; __syncthreads(); }
  const float x2 = red[0];
  float best = 1e30f; int bidx = 0;
#pragma unroll
  for (int cset = 0; cset < 2; ++cset) {
    const int c = cset * 256 + t;
    const float* cr = cb + (size_t)c * 256;
    float xc = 0.f, cc = 0.f;
    for (int dd = 0; dd < 256; dd += 4) {
      float4 cv = *(const float4*)(cr + dd);
      xc += xs[dd] * cv.x + xs[dd + 1] * cv.y + xs[dd + 2] * cv.z + xs[dd + 3] * cv.w;
      cc += cv.x * cv.x + cv.y * cv.y + cv.z * cv.z + cv.w * cv.w;
    }
    float d2 = x2 - 2.f * xc + cc;
    if (d2 < best) { best = d2; bidx = c; }
  }
  rv[t] = best; ri[t] = bidx; __syncthreads();
  for (int o = 128; o > 0; o >>= 1) {
    if (t < o) {
      if (rv[t + o] < rv[t] || (rv[t + o] == rv[t] && ri[t + o] < ri[t])) {
        rv[t] = rv[t + o]; ri[t] = ri[t + o];
      }
    }
    __syncthreads();
  }
  const int wi = ri[0];
  const float cval = cb[(size_t)wi * 256 + t];
  const float diff = xs[t] - cval;
  red[t] = diff * diff; __syncthreads();
  for (int o = 128; o > 0; o >>= 1) { if (t < o) red[t] += red[t + o]; __syncthreads(); }
  if (t == 0) { idx_out[r] = (float)wi; bestd2[r] = red[0]; }
  slots[(size_t)r * 256 + t] = cval;  // straight-through forward value
}

__global__ LB void k_commit(const float* __restrict__ bestd2, float* __restrict__ out) {
  const int t = threadIdx.x;
  __shared__ float red[256];
  float s = 0.f;
  for (int i = t; i < MS; i += 256) s += bestd2[i];
  red[t] = s; __syncthreads();
  for (int o = 128; o > 0; o >>= 1) { if (t < o) red[t] += red[t + o]; __syncthreads(); }
  if (t == 0) out[0] = red[0] / (float)(MS * 256);
}

__global__ LB void k_copy(const float* __restrict__ src, float* __restrict__ dst) {
  const int i = blockIdx.x * 256 + threadIdx.x;
  dst[i] = src[i];
}

extern "C" void kernel_launch(void* const* d_in, const int* in_sizes, int n_in,
                              void* d_out, int out_size, void* d_ws, size_t ws_size,
                              hipStream_t stream) {
  const float* features = (const float*)d_in[0];
  const float* cond = (const float*)d_in[1];
  const float* Wq = (const float*)d_in[2];
  const float* Wk = (const float*)d_in[3];
  const float* Wv = (const float*)d_in[4];
  const float* g_in = (const float*)d_in[5];
  const float* b_in = (const float*)d_in[6];
  const float* g_s = (const float*)d_in[7];
  const float* b_s = (const float*)d_in[8];
  const float* Wih = (const float*)d_in[9];
  const float* Whh = (const float*)d_in[10];
  const float* bih = (const float*)d_in[11];
  const float* bhh = (const float*)d_in[12];
  const float* cb = (const float*)d_in[13];
  float* out = (float*)d_out;

  // workspace layout (floats); total ~88 MB
  float* ws = (float*)d_ws;
  float* stats = ws;  ws += 2 * MF;
  float* kbuf = ws;   ws += (size_t)MF * 256;
  float* vbuf = ws;   ws += (size_t)MF * 256;
  float* attn = ws;   ws += (size_t)BATCH * NH * NSLOT * NFEAT;
  float* qbuf = ws;   ws += (size_t)MS * 256;
  float* snorm = ws;  ws += (size_t)MS * 256;
  float* slots = ws;  ws += (size_t)MS * 256;
  float* updb = ws;   ws += (size_t)MS * 256;
  float* gib = ws;    ws += (size_t)MS * 768;
  float* ghb = ws;    ws += (size_t)MS * 768;
  float* bestd2 = ws; ws += MS;

  float* out_slots = out;
  float* out_post = out + 196608;
  float* out_pre = out + 196608 + 786432;
  float* out_idx = out + 196608 + 786432 * 2;
  float* out_commit = out_idx + 768;

  // initial slots = conditioning
  hipMemcpyAsync(slots, cond, (size_t)MS * 256 * sizeof(float),
                 hipMemcpyDeviceToDevice, stream);

  // k/v depend only on features: compute once, reuse for both SA calls
  k_rowstats<<<MF, 256, 0, stream>>>(features, stats);
  k_lnkv<<<dim3(MF / 128, 4), 256, 0, stream>>>(features, stats, g_in, b_in, Wk, Wv, kbuf, vbuf);

  for (int call = 0; call < 2; ++call) {
    for (int it = 0; it < NITER; ++it) {
      k_ln_vec<<<MS, 256, 0, stream>>>(slots, g_s, b_s, snorm);
      k_gemm_nt<false><<<dim3(MS / 64, 4), 256, 0, stream>>>(snorm, Wq, nullptr, qbuf, 256);
      k_dots<<<BATCH * NH * 4, 256, 0, stream>>>(qbuf, kbuf, attn);
      k_upd<<<BATCH * NH, 256, 0, stream>>>(attn, vbuf, updb);
      k_gemm_nt<true><<<dim3(MS / 64, 12), 256, 0, stream>>>(updb, Wih, bih, gib, 768);
      k_gemm_nt<true><<<dim3(MS / 64, 12), 256, 0, stream>>>(slots, Whh, bhh, ghb, 768);
      k_gru<<<MS, 256, 0, stream>>>(gib, ghb, slots);
    }
    k_attnvis<<<BATCH * NSLOT * NFEAT / 256, 256, 0, stream>>>(attn, call ? out_post : out_pre);
    if (call == 0) {
      k_vq<<<MS, 256, 0, stream>>>(slots, cb, out_idx, bestd2);
      k_commit<<<1, 256, 0, stream>>>(bestd2, out_commit);
    }
  }
  k_copy<<<MS, 256, 0, stream>>>(slots, out_slots);
}